// Round 4
// baseline (235.730 us; speedup 1.0000x reference)
//
#include <hip/hip_runtime.h>
#include <hip/hip_bf16.h>
#include <math.h>

#define Bn 2048
#define Dn 512
#define Cn 16384

typedef __bf16 v8bf __attribute__((ext_vector_type(8)));
typedef float v4f __attribute__((ext_vector_type(4)));

// ---------------- prep: wave-per-row norms, scales, bf16 conversion ----------------
__global__ __launch_bounds__(256) void prep_kernel(
    const float* __restrict__ w, const float* __restrict__ x,
    __hip_bfloat16* __restrict__ wbf, __hip_bfloat16* __restrict__ xbf,
    float* __restrict__ fscale, float* __restrict__ ysqA, float* __restrict__ yrA,
    float* __restrict__ xsA, float* __restrict__ xrA)
{
  int gw = (blockIdx.x * 256 + threadIdx.x) >> 6;  // wave id == row
  int lane = threadIdx.x & 63;
  bool isW = gw < Cn;
  const float* src = isW ? (w + (size_t)gw * Dn) : (x + (size_t)(gw - Cn) * Dn);
  const float4* s4 = (const float4*)src;
  float4 a = s4[lane * 2], b = s4[lane * 2 + 1];  // 32 B/lane, coalesced
  float ss = a.x * a.x + a.y * a.y + a.z * a.z + a.w * a.w
           + b.x * b.x + b.y * b.y + b.z * b.z + b.w * b.w;
  #pragma unroll
  for (int d = 1; d < 64; d <<= 1) ss += __shfl_xor(ss, d);

  union { __hip_bfloat16 h[8]; int4 i4; } u;
  u.h[0] = __float2bfloat16(a.x); u.h[1] = __float2bfloat16(a.y);
  u.h[2] = __float2bfloat16(a.z); u.h[3] = __float2bfloat16(a.w);
  u.h[4] = __float2bfloat16(b.x); u.h[5] = __float2bfloat16(b.y);
  u.h[6] = __float2bfloat16(b.z); u.h[7] = __float2bfloat16(b.w);
  __hip_bfloat16* dst = isW ? (wbf + (size_t)gw * Dn) : (xbf + (size_t)(gw - Cn) * Dn);
  ((int4*)dst)[lane] = u.i4;  // 16 B/lane, coalesced

  if (lane == 0) {
    if (isW) {
      float n = fmaxf(sqrtf(ss), 1e-7f);
      float t = tanhf(n);           // c=1: tanh(sqrt_c * norm)
      float tc = fminf(t, 0.95f);   // radius clip folded into scale
      fscale[gw] = tc / n;          // proto = fscale * w
      float ys = tc * tc;           // ||proto||^2
      ysqA[gw] = ys;
      yrA[gw] = 1.f / (1.f - fminf(ys, 1.f - 1e-5f));
    } else {
      int r = gw - Cn;
      xsA[r] = ss;
      xrA[r] = 1.f / (1.f - fminf(ss, 1.f - 1e-5f));
    }
  }
}

// ---------------- LDS-free bf16 MFMA GEMM + slim epilogue ----------------
// K=512 is short and operands are L1/L2-resident: skip LDS entirely.
// Each wave streams its A/B fragments straight global->VGPR (16 rows x 64 B
// contiguous per frag load = perfectly coalesced dwordx4) with a register
// ping-pong; NO barriers, NO global_load_lds => the compiler emits
// fine-grained s_waitcnt vmcnt(N) instead of the structural vmcnt(0) drain
// that capped the LDS variants (m97-plateau). XCD banding keeps each XCD's
// W-band (2 MB) + X (2 MB) in its 4 MiB L2; intra-block 2x frag reuse hits L1.
__global__ __launch_bounds__(256) void gemm_kernel(
    const __hip_bfloat16* __restrict__ xbf, const __hip_bfloat16* __restrict__ wbf,
    const float* __restrict__ fscale, const float* __restrict__ ysqA,
    const float* __restrict__ yrA, const float* __restrict__ xsA,
    const float* __restrict__ xrA, float* __restrict__ partials)
{
  const int bid = blockIdx.x;
  const int xcd = bid & 7;          // round-robin dispatch across XCDs
  const int loc = bid >> 3;
  const int mt  = loc & 15;         // m fastest -> 16 blocks share one W band
  const int nt  = (xcd << 4) | (loc >> 4);
  const int mBase = mt * 128;
  const int nBase = nt * 128;
  const int tid = threadIdx.x;
  const int lane = tid & 63;
  const int wave = tid >> 6;
  const int quad = lane >> 4;
  const int l16 = lane & 15;
  const int waveM = wave >> 1;
  const int waveN = wave & 1;

  v4f acc[4][4];
  #pragma unroll
  for (int i = 0; i < 4; ++i)
    #pragma unroll
    for (int j = 0; j < 4; ++j)
      acc[i][j] = (v4f){0.f, 0.f, 0.f, 0.f};

  // per-frag base pointers: row = l16 (+16*i), k-chunk = quad*8 elements.
  // kt advances by 32 elements = 4 v8bf -> unrolled indices become immediates.
  const v8bf* Ap[4]; const v8bf* Wp[4];
  #pragma unroll
  for (int i = 0; i < 4; ++i) {
    Ap[i] = (const v8bf*)(xbf + (size_t)(mBase + waveM * 64 + i * 16 + l16) * Dn + quad * 8);
    Wp[i] = (const v8bf*)(wbf + (size_t)(nBase + waveN * 64 + i * 16 + l16) * Dn + quad * 8);
  }

  v8bf a0[4], b0[4], a1[4], b1[4];
  #pragma unroll
  for (int i = 0; i < 4; ++i) { a0[i] = Ap[i][0]; b0[i] = Wp[i][0]; }

  #pragma unroll
  for (int kp = 0; kp < 8; ++kp) {
    const int kt = kp * 2;
    if (kt + 1 < 16) {
      #pragma unroll
      for (int i = 0; i < 4; ++i) { a1[i] = Ap[i][(kt + 1) * 4]; b1[i] = Wp[i][(kt + 1) * 4]; }
    }
    #pragma unroll
    for (int i = 0; i < 4; ++i)
      #pragma unroll
      for (int j = 0; j < 4; ++j)
        acc[i][j] = __builtin_amdgcn_mfma_f32_16x16x32_bf16(a0[i], b0[j], acc[i][j], 0, 0, 0);
    if (kt + 2 < 16) {
      #pragma unroll
      for (int i = 0; i < 4; ++i) { a0[i] = Ap[i][(kt + 2) * 4]; b0[i] = Wp[i][(kt + 2) * 4]; }
    }
    #pragma unroll
    for (int i = 0; i < 4; ++i)
      #pragma unroll
      for (int j = 0; j < 4; ++j)
        acc[i][j] = __builtin_amdgcn_mfma_f32_16x16x32_bf16(a1[i], b1[j], acc[i][j], 0, 0, 0);
  }

  // ---- slim epilogue: z>=1 by construction => no extra clamps ----
  float ysqj[4], yrj[4], gj[4];
  #pragma unroll
  for (int j = 0; j < 4; ++j) {
    int col = nBase + waveN * 64 + j * 16 + l16;
    gj[j] = -2.f * fscale[col];
    ysqj[j] = ysqA[col];
    yrj[j] = yrA[col];
  }
  #pragma unroll
  for (int i = 0; i < 4; ++i) {
    #pragma unroll
    for (int r = 0; r < 4; ++r) {
      int row = mBase + waveM * 64 + i * 16 + quad * 4 + r;
      float xs = xsA[row];
      float xr2 = 2.f * xrA[row];
      float partial = 0.f;
      #pragma unroll
      for (int j = 0; j < 4; ++j) {
        float diff = fmaxf(fmaf(gj[j], acc[i][j][r], xs + ysqj[j]), 0.f);
        float z = fmaf(diff, xr2 * yrj[j], 1.f);
        float sq = sqrtf(fmaf(z, z, -1.f));
        float sims = __builtin_amdgcn_rcpf(z + sq);  // exp(-arccosh(z)), no cancellation
        partial += __expf(fmaf(128.f, sims, -64.f)); // fixed-shift logsumexp
      }
      partial += __shfl_xor(partial, 1);
      partial += __shfl_xor(partial, 2);
      partial += __shfl_xor(partial, 4);
      partial += __shfl_xor(partial, 8);
      if (l16 == 0) partials[(size_t)row * 256 + nt * 2 + waveN] = partial;
    }
  }
}

// ---------------- final: label fix + row term + grid mean (atomic) ----------------
__global__ __launch_bounds__(256) void final_kernel(
    const float* __restrict__ x, const float* __restrict__ w,
    const int* __restrict__ labels, const float* __restrict__ fscale,
    const float* __restrict__ ysqA, const float* __restrict__ yrA,
    const float* __restrict__ xsA, const float* __restrict__ xrA,
    const float* __restrict__ partials, float* __restrict__ out)
{
  int row = blockIdx.x * 4 + (threadIdx.x >> 6);  // wave per row
  int lane = threadIdx.x & 63;
  const float* pr = partials + (size_t)row * 256;
  float sum = pr[lane] + pr[lane + 64] + pr[lane + 128] + pr[lane + 192];

  int lab = labels[row];
  const float4* xv = (const float4*)(x + (size_t)row * Dn);
  const float4* wv = (const float4*)(w + (size_t)lab * Dn);
  float4 a0 = xv[lane * 2], a1 = xv[lane * 2 + 1];
  float4 b0 = wv[lane * 2], b1 = wv[lane * 2 + 1];
  float dot = a0.x * b0.x + a0.y * b0.y + a0.z * b0.z + a0.w * b0.w
            + a1.x * b1.x + a1.y * b1.y + a1.z * b1.z + a1.w * b1.w;
  #pragma unroll
  for (int d = 1; d < 64; d <<= 1) {
    sum += __shfl_xor(sum, d);
    dot += __shfl_xor(dot, d);
  }

  __shared__ float red[4];
  if (lane == 0) {
    float xy = fscale[lab] * dot;  // fp32 label logit
    float diff = fmaxf(xsA[row] + ysqA[lab] - 2.f * xy, 0.f);
    float z = fmaf(2.f * diff, xrA[row] * yrA[lab], 1.f);
    float sq = sqrtf(fmaf(z, z, -1.f));
    float sims = 1.f / (z + sq);
    float cosv = fmaf(2.f, sims, -1.f);
    float sine = sqrtf(fmaxf(fmaf(-cosv, cosv, 1.f), 1e-7f));
    float phi = (cosv > -0.8775825619f)
                    ? (cosv * 0.8775825619f - sine * 0.4794255386f)
                    : (cosv - 0.2397127693f);
    float e_cos = __expf(64.f * cosv);
    float e_phi = __expf(64.f * phi);
    // swap the plain-cos label term in the bf16 row-sum for the fp32 margin term
    red[threadIdx.x >> 6] = logf(sum - e_cos + e_phi) - 64.f * phi;
  }
  __syncthreads();
  if (threadIdx.x == 0)
    atomicAdd(out, (red[0] + red[1] + red[2] + red[3]) * (1.f / (float)Bn));
}

extern "C" void kernel_launch(void* const* d_in, const int* in_sizes, int n_in,
                              void* d_out, int out_size, void* d_ws, size_t ws_size,
                              hipStream_t stream) {
  (void)in_sizes; (void)n_in; (void)out_size; (void)ws_size;
  const float* emb = (const float*)d_in[0];
  const int* labels = (const int*)d_in[1];
  const float* weight = (const float*)d_in[2];
  float* out = (float*)d_out;

  char* p = (char*)d_ws;
  __hip_bfloat16* wbf = (__hip_bfloat16*)p; p += (size_t)Cn * Dn * 2;  // 16 MB
  __hip_bfloat16* xbf = (__hip_bfloat16*)p; p += (size_t)Bn * Dn * 2;  // 2 MB
  float* fscale = (float*)p; p += (size_t)Cn * 4;
  float* ysqA  = (float*)p; p += (size_t)Cn * 4;
  float* yrA   = (float*)p; p += (size_t)Cn * 4;
  float* xsA   = (float*)p; p += (size_t)Bn * 4;
  float* xrA   = (float*)p; p += (size_t)Bn * 4;
  float* partials = (float*)p; p += (size_t)Bn * 256 * 4;  // 2 MB, written-once

  hipMemsetAsync(out, 0, sizeof(float), stream);  // atomicAdd target
  prep_kernel<<<(Cn + Bn) / 4, 256, 0, stream>>>(weight, emb, wbf, xbf, fscale, ysqA, yrA, xsA, xrA);
  gemm_kernel<<<(Bn / 128) * (Cn / 128), 256, 0, stream>>>(
      xbf, wbf, fscale, ysqA, yrA, xsA, xrA, partials);
  final_kernel<<<Bn / 4, 256, 0, stream>>>(emb, weight, labels, fscale, ysqA, yrA, xsA, xrA, partials, out);
}

// Round 5
// 147.977 us; speedup vs baseline: 1.5930x; 1.5930x over previous
//
#include <hip/hip_runtime.h>
#include <hip/hip_bf16.h>
#include <math.h>

#define Bn 2048
#define Dn 512
#define Cn 16384

typedef __bf16 v8bf __attribute__((ext_vector_type(8)));
typedef float v4f __attribute__((ext_vector_type(4)));

// raw workgroup barrier: drains LDS ops only -- global loads stay in flight
// (unlike __syncthreads, which forces s_waitcnt vmcnt(0) and kills prefetch)
#define WG_BARRIER() asm volatile("s_waitcnt lgkmcnt(0)\n\ts_barrier" ::: "memory")

// ---------------- prep: wave-per-row norms, scales, bf16 conversion ----------------
__global__ __launch_bounds__(256) void prep_kernel(
    const float* __restrict__ w, const float* __restrict__ x,
    __hip_bfloat16* __restrict__ wbf, __hip_bfloat16* __restrict__ xbf,
    float* __restrict__ fscale, float* __restrict__ ysqA, float* __restrict__ yrA,
    float* __restrict__ xsA, float* __restrict__ xrA)
{
  int gw = (blockIdx.x * 256 + threadIdx.x) >> 6;  // wave id == row
  int lane = threadIdx.x & 63;
  bool isW = gw < Cn;
  const float* src = isW ? (w + (size_t)gw * Dn) : (x + (size_t)(gw - Cn) * Dn);
  const float4* s4 = (const float4*)src;
  float4 a = s4[lane * 2], b = s4[lane * 2 + 1];  // 32 B/lane, coalesced
  float ss = a.x * a.x + a.y * a.y + a.z * a.z + a.w * a.w
           + b.x * b.x + b.y * b.y + b.z * b.z + b.w * b.w;
  #pragma unroll
  for (int d = 1; d < 64; d <<= 1) ss += __shfl_xor(ss, d);

  union { __hip_bfloat16 h[8]; int4 i4; } u;
  u.h[0] = __float2bfloat16(a.x); u.h[1] = __float2bfloat16(a.y);
  u.h[2] = __float2bfloat16(a.z); u.h[3] = __float2bfloat16(a.w);
  u.h[4] = __float2bfloat16(b.x); u.h[5] = __float2bfloat16(b.y);
  u.h[6] = __float2bfloat16(b.z); u.h[7] = __float2bfloat16(b.w);
  __hip_bfloat16* dst = isW ? (wbf + (size_t)gw * Dn) : (xbf + (size_t)(gw - Cn) * Dn);
  ((int4*)dst)[lane] = u.i4;  // 16 B/lane, coalesced

  if (lane == 0) {
    if (isW) {
      float n = fmaxf(sqrtf(ss), 1e-7f);
      float t = tanhf(n);           // c=1: tanh(sqrt_c * norm)
      float tc = fminf(t, 0.95f);   // radius clip folded into scale
      fscale[gw] = tc / n;          // proto = fscale * w
      float ys = tc * tc;           // ||proto||^2
      ysqA[gw] = ys;
      yrA[gw] = 1.f / (1.f - fminf(ys, 1.f - 1e-5f));
    } else {
      int r = gw - Cn;
      xsA[r] = ss;
      xrA[r] = 1.f / (1.f - fminf(ss, 1.f - 1e-5f));
    }
  }
}

// ---------------- bf16 MFMA GEMM: VGPR-staged pipeline, raw barriers ----------------
// 128x128 tile, BK=32, 16 iters. AITER-style: buffer_load -> VGPR (2 iters of
// flight across raw barriers) -> ds_write -> LDS dbuf (2x16KB) -> ds_read ->
// MFMA. One lgkmcnt(0)+s_barrier per iter; NO vmcnt(0) drain anywhere in loop.
// Race-freedom: buf written in iter k is read in k+1 after the barrier; buf
// read in iter k is rewritten in k+1 after the same barrier, and each wave's
// reads completed (lgkmcnt 0) before it arrived.
__global__ __launch_bounds__(256) void gemm_kernel(
    const __hip_bfloat16* __restrict__ xbf, const __hip_bfloat16* __restrict__ wbf,
    const float* __restrict__ fscale, const float* __restrict__ ysqA,
    const float* __restrict__ yrA, const float* __restrict__ xsA,
    const float* __restrict__ xrA, float* __restrict__ partials)
{
  __shared__ int4 ldsv[2048];  // 32 KB: [A0 8K][W0 8K][A1 8K][W1 8K]
  char* lds = (char*)ldsv;

  const int bid = blockIdx.x;
  const int xcd = bid & 7;          // round-robin dispatch across XCDs
  const int loc = bid >> 3;
  const int mt  = loc & 15;         // m fastest -> 16 blocks share one W band
  const int nt  = (xcd << 4) | (loc >> 4);
  const int mBase = mt * 128;
  const int nBase = nt * 128;
  const int tid = threadIdx.x;
  const int lane = tid & 63;
  const int wave = tid >> 6;
  const int quad = lane >> 4;
  const int l16 = lane & 15;
  const int waveM = wave >> 1;
  const int waveN = wave & 1;

  v4f acc[4][4];
  #pragma unroll
  for (int i = 0; i < 4; ++i)
    #pragma unroll
    for (int j = 0; j < 4; ++j)
      acc[i][j] = (v4f){0.f, 0.f, 0.f, 0.f};

  // staging: per iter each tile = 128 rows x 64 B = 512 chunks of 16 B;
  // thread owns chunks tid and tid+256 of A and of W.
  // LDS col swizzle: global chunk-col c stored at col c^(r&3)  (self-inverse).
  const int r0 = tid >> 2,          c0g = tid & 3;
  const int r1 = (tid + 256) >> 2,  c1g = tid & 3;  // (tid+256)&3 == tid&3
  const char* gA0 = (const char*)xbf + (size_t)(mBase + r0) * (Dn * 2) + c0g * 16;
  const char* gA1 = (const char*)xbf + (size_t)(mBase + r1) * (Dn * 2) + c1g * 16;
  const char* gW0 = (const char*)wbf + (size_t)(nBase + r0) * (Dn * 2) + c0g * 16;
  const char* gW1 = (const char*)wbf + (size_t)(nBase + r1) * (Dn * 2) + c1g * 16;
  const int lo0 = r0 * 64 + ((c0g ^ (r0 & 3)) * 16);
  const int lo1 = r1 * 64 + ((c1g ^ (r1 & 3)) * 16);

  // frag read offsets (within an 8 KB region)
  int aoffs[4], boffs[4];
  #pragma unroll
  for (int i = 0; i < 4; ++i) {
    int ra = waveM * 64 + i * 16 + l16;
    aoffs[i] = ra * 64 + ((quad ^ (ra & 3)) * 16);
    int rb = waveN * 64 + i * 16 + l16;
    boffs[i] = rb * 64 + ((quad ^ (rb & 3)) * 16);
  }

  // prologue: tile0 -> LDS buf0; tile1 -> t[1]; tile2 -> t[0]
  int4 tA[2][2], tW[2][2];
  tA[0][0] = *(const int4*)gA0;        tA[0][1] = *(const int4*)gA1;
  tW[0][0] = *(const int4*)gW0;        tW[0][1] = *(const int4*)gW1;
  *(int4*)(lds + lo0) = tA[0][0];      *(int4*)(lds + lo1) = tA[0][1];
  *(int4*)(lds + 8192 + lo0) = tW[0][0]; *(int4*)(lds + 8192 + lo1) = tW[0][1];
  tA[1][0] = *(const int4*)(gA0 + 64);  tA[1][1] = *(const int4*)(gA1 + 64);
  tW[1][0] = *(const int4*)(gW0 + 64);  tW[1][1] = *(const int4*)(gW1 + 64);
  tA[0][0] = *(const int4*)(gA0 + 128); tA[0][1] = *(const int4*)(gA1 + 128);
  tW[0][0] = *(const int4*)(gW0 + 128); tW[0][1] = *(const int4*)(gW1 + 128);

  #pragma unroll
  for (int kt = 0; kt < 16; ++kt) {
    const int cur = kt & 1;
    WG_BARRIER();  // lgkmcnt(0)+s_barrier only: global prefetch stays in flight
    const char* Ab = lds + cur * 16384;
    const char* Wb = Ab + 8192;
    v8bf af[4], bfr[4];
    #pragma unroll
    for (int i = 0; i < 4; ++i) af[i] = *(const v8bf*)(Ab + aoffs[i]);
    #pragma unroll
    for (int j = 0; j < 4; ++j) bfr[j] = *(const v8bf*)(Wb + boffs[j]);
    if (kt < 15) {  // stage tile kt+1 (in VGPRs) into the other LDS buffer
      const int par = (kt + 1) & 1;
      char* An = lds + (cur ^ 1) * 16384;
      *(int4*)(An + lo0) = tA[par][0];
      *(int4*)(An + lo1) = tA[par][1];
      *(int4*)(An + 8192 + lo0) = tW[par][0];
      *(int4*)(An + 8192 + lo1) = tW[par][1];
      if (kt + 3 < 16) {  // refill regs with tile kt+3: ~2 iters of flight
        tA[par][0] = *(const int4*)(gA0 + (kt + 3) * 64);
        tA[par][1] = *(const int4*)(gA1 + (kt + 3) * 64);
        tW[par][0] = *(const int4*)(gW0 + (kt + 3) * 64);
        tW[par][1] = *(const int4*)(gW1 + (kt + 3) * 64);
      }
    }
    #pragma unroll
    for (int i = 0; i < 4; ++i)
      #pragma unroll
      for (int j = 0; j < 4; ++j)
        acc[i][j] = __builtin_amdgcn_mfma_f32_16x16x32_bf16(af[i], bfr[j], acc[i][j], 0, 0, 0);
  }

  // ---- epilogue: partial sums of e^{u}, u = 128*sims (e^{+64}-scaled) ----
  float ysqj[4], yrj[4], gj[4];
  #pragma unroll
  for (int j = 0; j < 4; ++j) {
    int col = nBase + waveN * 64 + j * 16 + l16;
    gj[j] = -2.f * fscale[col];
    ysqj[j] = ysqA[col];
    yrj[j] = yrA[col];
  }
  #pragma unroll
  for (int i = 0; i < 4; ++i) {
    #pragma unroll
    for (int r = 0; r < 4; ++r) {
      int row = mBase + waveM * 64 + i * 16 + quad * 4 + r;
      float xs = xsA[row];
      float xr2 = 2.f * xrA[row];
      float partial = 0.f;
      if (xs >= 0.99999f) {
        // clipped row: xr=1e5 -> z>=~1e4 -> u=64/z<=~1e-2.
        // sims=1/(z+sqrt(z^2-1))~=1/(2z) (rel err 1/(4z^2)); e^u ~= 1+u+u^2/2.
        #pragma unroll
        for (int j = 0; j < 4; ++j) {
          float d = fmaxf(fmaf(gj[j], acc[i][j][r], xs + ysqj[j]), 0.f);
          float z = fmaf(d, xr2 * yrj[j], 1.f);
          float u = 64.f * __builtin_amdgcn_rcpf(z);
          partial += fmaf(u, fmaf(0.5f, u, 1.f), 1.f);
        }
      } else {
        // rare unclipped row: exact path
        #pragma unroll
        for (int j = 0; j < 4; ++j) {
          float d = fmaxf(fmaf(gj[j], acc[i][j][r], xs + ysqj[j]), 0.f);
          float z = fmaf(d, xr2 * yrj[j], 1.f);
          float sq = sqrtf(fmaf(z, z, -1.f));
          float u = 128.f * __builtin_amdgcn_rcpf(z + sq);
          partial += __expf(u);
        }
      }
      partial += __shfl_xor(partial, 1);
      partial += __shfl_xor(partial, 2);
      partial += __shfl_xor(partial, 4);
      partial += __shfl_xor(partial, 8);
      if (l16 == 0) partials[(size_t)row * 256 + nt * 2 + waveN] = partial;
    }
  }
}

// ---------------- final: label fix + row term + grid mean (atomic) ----------------
// partials are e^{+64}-scaled: S = sum_j e^{u_j}. term = -64 + log(S - e^{u_lab}
// + e^{64(phi+1)}) - 64*phi.
__global__ __launch_bounds__(256) void final_kernel(
    const float* __restrict__ x, const float* __restrict__ w,
    const int* __restrict__ labels, const float* __restrict__ fscale,
    const float* __restrict__ ysqA, const float* __restrict__ yrA,
    const float* __restrict__ xsA, const float* __restrict__ xrA,
    const float* __restrict__ partials, float* __restrict__ out)
{
  int row = blockIdx.x * 4 + (threadIdx.x >> 6);  // wave per row
  int lane = threadIdx.x & 63;
  const float* pr = partials + (size_t)row * 256;
  float sum = pr[lane] + pr[lane + 64] + pr[lane + 128] + pr[lane + 192];

  int lab = labels[row];
  const float4* xv = (const float4*)(x + (size_t)row * Dn);
  const float4* wv = (const float4*)(w + (size_t)lab * Dn);
  float4 a0 = xv[lane * 2], a1 = xv[lane * 2 + 1];
  float4 b0 = wv[lane * 2], b1 = wv[lane * 2 + 1];
  float dot = a0.x * b0.x + a0.y * b0.y + a0.z * b0.z + a0.w * b0.w
            + a1.x * b1.x + a1.y * b1.y + a1.z * b1.z + a1.w * b1.w;
  #pragma unroll
  for (int d = 1; d < 64; d <<= 1) {
    sum += __shfl_xor(sum, d);
    dot += __shfl_xor(dot, d);
  }

  __shared__ float red[4];
  if (lane == 0) {
    float xy = fscale[lab] * dot;  // fp32 exact label logit
    float diff = fmaxf(xsA[row] + ysqA[lab] - 2.f * xy, 0.f);
    float z = fmaf(2.f * diff, xrA[row] * yrA[lab], 1.f);
    float sq = sqrtf(fmaf(z, z, -1.f));
    float sims = 1.f / (z + sq);
    float u_lab = 128.f * sims;
    float cosv = fmaf(2.f, sims, -1.f);
    float sine = sqrtf(fmaxf(fmaf(-cosv, cosv, 1.f), 1e-7f));
    float phi = (cosv > -0.8775825619f)
                    ? (cosv * 0.8775825619f - sine * 0.4794255386f)
                    : (cosv - 0.2397127693f);
    float e_lab = __expf(u_lab);                          // e^{+64}-scaled cos term
    float e_phi = __expf(fminf(64.f * phi + 64.f, 80.f)); // scaled margin term
    red[threadIdx.x >> 6] = logf(sum - e_lab + e_phi) - 64.f * phi - 64.f;
  }
  __syncthreads();
  if (threadIdx.x == 0)
    atomicAdd(out, (red[0] + red[1] + red[2] + red[3]) * (1.f / (float)Bn));
}

extern "C" void kernel_launch(void* const* d_in, const int* in_sizes, int n_in,
                              void* d_out, int out_size, void* d_ws, size_t ws_size,
                              hipStream_t stream) {
  (void)in_sizes; (void)n_in; (void)out_size; (void)ws_size;
  const float* emb = (const float*)d_in[0];
  const int* labels = (const int*)d_in[1];
  const float* weight = (const float*)d_in[2];
  float* out = (float*)d_out;

  char* p = (char*)d_ws;
  __hip_bfloat16* wbf = (__hip_bfloat16*)p; p += (size_t)Cn * Dn * 2;  // 16 MB
  __hip_bfloat16* xbf = (__hip_bfloat16*)p; p += (size_t)Bn * Dn * 2;  // 2 MB
  float* fscale = (float*)p; p += (size_t)Cn * 4;
  float* ysqA  = (float*)p; p += (size_t)Cn * 4;
  float* yrA   = (float*)p; p += (size_t)Cn * 4;
  float* xsA   = (float*)p; p += (size_t)Bn * 4;
  float* xrA   = (float*)p; p += (size_t)Bn * 4;
  float* partials = (float*)p; p += (size_t)Bn * 256 * 4;  // 2 MB, written-once

  hipMemsetAsync(out, 0, sizeof(float), stream);  // atomicAdd target
  prep_kernel<<<(Cn + Bn) / 4, 256, 0, stream>>>(weight, emb, wbf, xbf, fscale, ysqA, yrA, xsA, xrA);
  gemm_kernel<<<(Bn / 128) * (Cn / 128), 256, 0, stream>>>(
      xbf, wbf, fscale, ysqA, yrA, xsA, xrA, partials);
  final_kernel<<<Bn / 4, 256, 0, stream>>>(emb, weight, labels, fscale, ysqA, yrA, xsA, xrA, partials, out);
}

// Round 6
// 141.643 us; speedup vs baseline: 1.6643x; 1.0447x over previous
//
#include <hip/hip_runtime.h>
#include <hip/hip_bf16.h>
#include <math.h>

#define Bn 2048
#define Dn 512
#define Cn 16384

typedef __bf16 v8bf __attribute__((ext_vector_type(8)));
typedef float v4f __attribute__((ext_vector_type(4)));

// fine-grained waits + raw barriers: the AITER pattern __syncthreads can't express
#define WAIT_VM4()      asm volatile("s_waitcnt vmcnt(4)" ::: "memory")
#define WAIT_VM0()      asm volatile("s_waitcnt vmcnt(0)" ::: "memory")
#define RAW_BAR()       asm volatile("s_barrier" ::: "memory")
#define LGKM0_BAR()     asm volatile("s_waitcnt lgkmcnt(0)\n\ts_barrier" ::: "memory")

__device__ __forceinline__ void async16(const void* g, void* l) {
  __builtin_amdgcn_global_load_lds(
      (const __attribute__((address_space(1))) char*)g,
      (__attribute__((address_space(3))) char*)l, 16, 0, 0);
}

// ---------------- prep: wave-per-row norms, scales, bf16 conversion ----------------
__global__ __launch_bounds__(256) void prep_kernel(
    const float* __restrict__ w, const float* __restrict__ x,
    __hip_bfloat16* __restrict__ wbf, __hip_bfloat16* __restrict__ xbf,
    float* __restrict__ fscale, float* __restrict__ ysqA, float* __restrict__ yrA,
    float* __restrict__ xsA, float* __restrict__ xrA)
{
  int gw = (blockIdx.x * 256 + threadIdx.x) >> 6;  // wave id == row
  int lane = threadIdx.x & 63;
  bool isW = gw < Cn;
  const float* src = isW ? (w + (size_t)gw * Dn) : (x + (size_t)(gw - Cn) * Dn);
  const float4* s4 = (const float4*)src;
  float4 a = s4[lane * 2], b = s4[lane * 2 + 1];  // 32 B/lane, coalesced
  float ss = a.x * a.x + a.y * a.y + a.z * a.z + a.w * a.w
           + b.x * b.x + b.y * b.y + b.z * b.z + b.w * b.w;
  #pragma unroll
  for (int d = 1; d < 64; d <<= 1) ss += __shfl_xor(ss, d);

  union { __hip_bfloat16 h[8]; int4 i4; } u;
  u.h[0] = __float2bfloat16(a.x); u.h[1] = __float2bfloat16(a.y);
  u.h[2] = __float2bfloat16(a.z); u.h[3] = __float2bfloat16(a.w);
  u.h[4] = __float2bfloat16(b.x); u.h[5] = __float2bfloat16(b.y);
  u.h[6] = __float2bfloat16(b.z); u.h[7] = __float2bfloat16(b.w);
  __hip_bfloat16* dst = isW ? (wbf + (size_t)gw * Dn) : (xbf + (size_t)(gw - Cn) * Dn);
  ((int4*)dst)[lane] = u.i4;  // 16 B/lane, coalesced

  if (lane == 0) {
    if (isW) {
      float n = fmaxf(sqrtf(ss), 1e-7f);
      float t = tanhf(n);           // c=1: tanh(sqrt_c * norm)
      float tc = fminf(t, 0.95f);   // radius clip folded into scale
      fscale[gw] = tc / n;          // proto = fscale * w
      float ys = tc * tc;           // ||proto||^2
      ysqA[gw] = ys;
      yrA[gw] = 1.f / (1.f - fminf(ys, 1.f - 1e-5f));
    } else {
      int r = gw - Cn;
      xsA[r] = ss;
      xrA[r] = 1.f / (1.f - fminf(ss, 1.f - 1e-5f));
    }
  }
}

// ------- bf16 MFMA GEMM: global_load_lds dbuf + fine-grained vmcnt pipeline -------
// 128x128 tile, BK=32, 16 iters. Loads go straight global->LDS (no ds_write:
// halves LDS pipe traffic vs R5, which was LDS-bound at 512 cyc/iter vs 155
// MFMA). Hand-placed s_waitcnt vmcnt(4) + raw s_barrier keeps the next tile's
// 4 loads in flight across the barrier (~2 iters of latency cover) -- the
// structural vmcnt(0) drain of __syncthreads never happens.
// Race-freedom: barrier-1 follows each wave's vmcnt wait => all loads of
// buf[cur] landed before any read; barrier-2 follows lgkmcnt(0) => all waves'
// reads of buf[cur] completed before tile kt+2's loads are issued into it.
// LDS dest of global_load_lds must be wave-uniform base + lane*16 (m104), so
// the LDS layout is linear; bank-swizzle is done on the GLOBAL source column
// (slot s <- global chunk col (s&3)^(r&3)), which R3 measured conflict-free.
__global__ __launch_bounds__(256) void gemm_kernel(
    const __hip_bfloat16* __restrict__ xbf, const __hip_bfloat16* __restrict__ wbf,
    const float* __restrict__ fscale, const float* __restrict__ ysqA,
    const float* __restrict__ yrA, const float* __restrict__ xsA,
    const float* __restrict__ xrA, float* __restrict__ partials)
{
  __shared__ int4 ldsv[2048];  // 32 KB: buf0 [A 8K][W 8K] | buf1 [A 8K][W 8K]
  char* lds = (char*)ldsv;

  const int bid = blockIdx.x;
  const int xcd = bid & 7;          // round-robin dispatch across XCDs
  const int loc = bid >> 3;
  const int mt  = loc & 15;         // m fastest -> 16 blocks share one W band
  const int nt  = (xcd << 4) | (loc >> 4);
  const int mBase = mt * 128;
  const int nBase = nt * 128;
  const int tid = threadIdx.x;
  const int lane = tid & 63;
  const int wave = tid >> 6;
  const int quad = lane >> 4;
  const int l16 = lane & 15;
  const int waveM = wave >> 1;
  const int waveN = wave & 1;

  v4f acc[4][4];
  #pragma unroll
  for (int i = 0; i < 4; ++i)
    #pragma unroll
    for (int j = 0; j < 4; ++j)
      acc[i][j] = (v4f){0.f, 0.f, 0.f, 0.f};

  // thread owns LDS slots tid and tid+256 of A and of W (4 async16/iter).
  // slot s: row r=s>>2, slot-col s&3, global chunk col (s&3)^(r&3).
  const int s0 = tid, s1 = tid + 256;
  const int r0 = s0 >> 2, c0 = (s0 & 3) ^ (r0 & 3);
  const int r1 = s1 >> 2, c1 = (s1 & 3) ^ (r1 & 3);
  const char* gA0 = (const char*)xbf + (size_t)(mBase + r0) * (Dn * 2) + c0 * 16;
  const char* gA1 = (const char*)xbf + (size_t)(mBase + r1) * (Dn * 2) + c1 * 16;
  const char* gW0 = (const char*)wbf + (size_t)(nBase + r0) * (Dn * 2) + c0 * 16;
  const char* gW1 = (const char*)wbf + (size_t)(nBase + r1) * (Dn * 2) + c1 * 16;
  const int lo0 = s0 * 16, lo1 = s1 * 16;

  // frag read offsets within an 8 KB region (swizzle-aware)
  int aoffs[4], boffs[4];
  #pragma unroll
  for (int i = 0; i < 4; ++i) {
    int ra = waveM * 64 + i * 16 + l16;
    aoffs[i] = ra * 64 + ((quad ^ (ra & 3)) * 16);
    int rb = waveN * 64 + i * 16 + l16;
    boffs[i] = rb * 64 + ((quad ^ (rb & 3)) * 16);
  }

  // prologue: tiles 0 and 1 -> buffers 0 and 1 (8 loads in flight)
  #pragma unroll
  for (int t = 0; t < 2; ++t) {
    char* b = lds + t * 16384;
    async16(gA0 + t * 64, b + lo0);
    async16(gA1 + t * 64, b + lo1);
    async16(gW0 + t * 64, b + 8192 + lo0);
    async16(gW1 + t * 64, b + 8192 + lo1);
  }

  #pragma unroll
  for (int kt = 0; kt < 16; ++kt) {
    const int cur = kt & 1;
    if (kt < 15) { WAIT_VM4(); } else { WAIT_VM0(); }  // buf[cur]'s 4 loads landed
    RAW_BAR();                                          // ...for ALL waves
    char* Ab = lds + cur * 16384;
    char* Wb = Ab + 8192;
    v8bf af[4], bfr[4];
    #pragma unroll
    for (int i = 0; i < 4; ++i) af[i] = *(const v8bf*)(Ab + aoffs[i]);
    #pragma unroll
    for (int j = 0; j < 4; ++j) bfr[j] = *(const v8bf*)(Wb + boffs[j]);
    LGKM0_BAR();  // all waves' reads of buf[cur] done -> safe to rewrite it
    if (kt + 2 < 16) {  // tile kt+2 into buf[cur]: ~2 iters of flight
      async16(gA0 + (kt + 2) * 64, Ab + lo0);
      async16(gA1 + (kt + 2) * 64, Ab + lo1);
      async16(gW0 + (kt + 2) * 64, Wb + lo0);
      async16(gW1 + (kt + 2) * 64, Wb + lo1);
    }
    #pragma unroll
    for (int i = 0; i < 4; ++i)
      #pragma unroll
      for (int j = 0; j < 4; ++j)
        acc[i][j] = __builtin_amdgcn_mfma_f32_16x16x32_bf16(af[i], bfr[j], acc[i][j], 0, 0, 0);
  }

  // ---- epilogue: partial sums of e^{u}, u = 128*sims (e^{+64}-scaled) ----
  float ysqj[4], yrj[4], gj[4];
  #pragma unroll
  for (int j = 0; j < 4; ++j) {
    int col = nBase + waveN * 64 + j * 16 + l16;
    gj[j] = -2.f * fscale[col];
    ysqj[j] = ysqA[col];
    yrj[j] = yrA[col];
  }
  #pragma unroll
  for (int i = 0; i < 4; ++i) {
    #pragma unroll
    for (int r = 0; r < 4; ++r) {
      int row = mBase + waveM * 64 + i * 16 + quad * 4 + r;
      float xs = xsA[row];
      float xr2 = 2.f * xrA[row];
      float partial = 0.f;
      if (xs >= 0.99999f) {
        // clipped row: xr=1e5 -> z>=~1e4 -> u=64/z<=~1e-2.
        // sims~=1/(2z) (rel err 1/(4z^2)); e^u ~= 1+u+u^2/2 (err u^3/6).
        #pragma unroll
        for (int j = 0; j < 4; ++j) {
          float d = fmaxf(fmaf(gj[j], acc[i][j][r], xs + ysqj[j]), 0.f);
          float z = fmaf(d, xr2 * yrj[j], 1.f);
          float u = 64.f * __builtin_amdgcn_rcpf(z);
          partial += fmaf(u, fmaf(0.5f, u, 1.f), 1.f);
        }
      } else {
        // rare unclipped row: exact path
        #pragma unroll
        for (int j = 0; j < 4; ++j) {
          float d = fmaxf(fmaf(gj[j], acc[i][j][r], xs + ysqj[j]), 0.f);
          float z = fmaf(d, xr2 * yrj[j], 1.f);
          float sq = sqrtf(fmaf(z, z, -1.f));
          float u = 128.f * __builtin_amdgcn_rcpf(z + sq);
          partial += __expf(u);
        }
      }
      partial += __shfl_xor(partial, 1);
      partial += __shfl_xor(partial, 2);
      partial += __shfl_xor(partial, 4);
      partial += __shfl_xor(partial, 8);
      if (l16 == 0) partials[(size_t)row * 256 + nt * 2 + waveN] = partial;
    }
  }
}

// ---------------- final: label fix + row term + grid mean (atomic) ----------------
// partials are e^{+64}-scaled: S = sum_j e^{u_j}. term = -64 + log(S - e^{u_lab}
// + e^{64(phi+1)}) - 64*phi.
__global__ __launch_bounds__(256) void final_kernel(
    const float* __restrict__ x, const float* __restrict__ w,
    const int* __restrict__ labels, const float* __restrict__ fscale,
    const float* __restrict__ ysqA, const float* __restrict__ yrA,
    const float* __restrict__ xsA, const float* __restrict__ xrA,
    const float* __restrict__ partials, float* __restrict__ out)
{
  int row = blockIdx.x * 4 + (threadIdx.x >> 6);  // wave per row
  int lane = threadIdx.x & 63;
  const float* pr = partials + (size_t)row * 256;
  float sum = pr[lane] + pr[lane + 64] + pr[lane + 128] + pr[lane + 192];

  int lab = labels[row];
  const float4* xv = (const float4*)(x + (size_t)row * Dn);
  const float4* wv = (const float4*)(w + (size_t)lab * Dn);
  float4 a0 = xv[lane * 2], a1 = xv[lane * 2 + 1];
  float4 b0 = wv[lane * 2], b1 = wv[lane * 2 + 1];
  float dot = a0.x * b0.x + a0.y * b0.y + a0.z * b0.z + a0.w * b0.w
            + a1.x * b1.x + a1.y * b1.y + a1.z * b1.z + a1.w * b1.w;
  #pragma unroll
  for (int d = 1; d < 64; d <<= 1) {
    sum += __shfl_xor(sum, d);
    dot += __shfl_xor(dot, d);
  }

  __shared__ float red[4];
  if (lane == 0) {
    float xy = fscale[lab] * dot;  // fp32 exact label logit
    float diff = fmaxf(xsA[row] + ysqA[lab] - 2.f * xy, 0.f);
    float z = fmaf(2.f * diff, xrA[row] * yrA[lab], 1.f);
    float sq = sqrtf(fmaf(z, z, -1.f));
    float sims = 1.f / (z + sq);
    float u_lab = 128.f * sims;
    float cosv = fmaf(2.f, sims, -1.f);
    float sine = sqrtf(fmaxf(fmaf(-cosv, cosv, 1.f), 1e-7f));
    float phi = (cosv > -0.8775825619f)
                    ? (cosv * 0.8775825619f - sine * 0.4794255386f)
                    : (cosv - 0.2397127693f);
    float e_lab = __expf(u_lab);                          // e^{+64}-scaled cos term
    float e_phi = __expf(fminf(64.f * phi + 64.f, 80.f)); // scaled margin term
    red[threadIdx.x >> 6] = logf(sum - e_lab + e_phi) - 64.f * phi - 64.f;
  }
  __syncthreads();
  if (threadIdx.x == 0)
    atomicAdd(out, (red[0] + red[1] + red[2] + red[3]) * (1.f / (float)Bn));
}

extern "C" void kernel_launch(void* const* d_in, const int* in_sizes, int n_in,
                              void* d_out, int out_size, void* d_ws, size_t ws_size,
                              hipStream_t stream) {
  (void)in_sizes; (void)n_in; (void)out_size; (void)ws_size;
  const float* emb = (const float*)d_in[0];
  const int* labels = (const int*)d_in[1];
  const float* weight = (const float*)d_in[2];
  float* out = (float*)d_out;

  char* p = (char*)d_ws;
  __hip_bfloat16* wbf = (__hip_bfloat16*)p; p += (size_t)Cn * Dn * 2;  // 16 MB
  __hip_bfloat16* xbf = (__hip_bfloat16*)p; p += (size_t)Bn * Dn * 2;  // 2 MB
  float* fscale = (float*)p; p += (size_t)Cn * 4;
  float* ysqA  = (float*)p; p += (size_t)Cn * 4;
  float* yrA   = (float*)p; p += (size_t)Cn * 4;
  float* xsA   = (float*)p; p += (size_t)Bn * 4;
  float* xrA   = (float*)p; p += (size_t)Bn * 4;
  float* partials = (float*)p; p += (size_t)Bn * 256 * 4;  // 2 MB, written-once

  hipMemsetAsync(out, 0, sizeof(float), stream);  // atomicAdd target
  prep_kernel<<<(Cn + Bn) / 4, 256, 0, stream>>>(weight, emb, wbf, xbf, fscale, ysqA, yrA, xsA, xrA);
  gemm_kernel<<<(Bn / 128) * (Cn / 128), 256, 0, stream>>>(
      xbf, wbf, fscale, ysqA, yrA, xsA, xrA, partials);
  final_kernel<<<Bn / 4, 256, 0, stream>>>(emb, weight, labels, fscale, ysqA, yrA, xsA, xrA, partials, out);
}

// Round 7
// 137.533 us; speedup vs baseline: 1.7140x; 1.0299x over previous
//
#include <hip/hip_runtime.h>
#include <hip/hip_bf16.h>
#include <math.h>

#define Bn 2048
#define Dn 512
#define Cn 16384

typedef __bf16 v8bf __attribute__((ext_vector_type(8)));
typedef float v4f __attribute__((ext_vector_type(4)));

#define WAIT_VM6()  asm volatile("s_waitcnt vmcnt(6)" ::: "memory")
#define WAIT_VM0()  asm volatile("s_waitcnt vmcnt(0)" ::: "memory")
#define RAW_BAR()   asm volatile("s_barrier" ::: "memory")
#define LGKM0_BAR() asm volatile("s_waitcnt lgkmcnt(0)\n\ts_barrier" ::: "memory")

__device__ __forceinline__ void async16(const void* g, void* l) {
  __builtin_amdgcn_global_load_lds(
      (const __attribute__((address_space(1))) char*)g,
      (__attribute__((address_space(3))) char*)l, 16, 0, 0);
}

// ---------------- prep: wave-per-row norms, scales, bf16 conversion ----------------
__global__ __launch_bounds__(256) void prep_kernel(
    const float* __restrict__ w, const float* __restrict__ x,
    __hip_bfloat16* __restrict__ wbf, __hip_bfloat16* __restrict__ xbf,
    float* __restrict__ fscale, float* __restrict__ ysqA, float* __restrict__ yrA,
    float* __restrict__ xsA, float* __restrict__ xrA)
{
  int gw = (blockIdx.x * 256 + threadIdx.x) >> 6;  // wave id == row
  int lane = threadIdx.x & 63;
  bool isW = gw < Cn;
  const float* src = isW ? (w + (size_t)gw * Dn) : (x + (size_t)(gw - Cn) * Dn);
  const float4* s4 = (const float4*)src;
  float4 a = s4[lane * 2], b = s4[lane * 2 + 1];  // 32 B/lane, coalesced
  float ss = a.x * a.x + a.y * a.y + a.z * a.z + a.w * a.w
           + b.x * b.x + b.y * b.y + b.z * b.z + b.w * b.w;
  #pragma unroll
  for (int d = 1; d < 64; d <<= 1) ss += __shfl_xor(ss, d);

  union { __hip_bfloat16 h[8]; int4 i4; } u;
  u.h[0] = __float2bfloat16(a.x); u.h[1] = __float2bfloat16(a.y);
  u.h[2] = __float2bfloat16(a.z); u.h[3] = __float2bfloat16(a.w);
  u.h[4] = __float2bfloat16(b.x); u.h[5] = __float2bfloat16(b.y);
  u.h[6] = __float2bfloat16(b.z); u.h[7] = __float2bfloat16(b.w);
  __hip_bfloat16* dst = isW ? (wbf + (size_t)gw * Dn) : (xbf + (size_t)(gw - Cn) * Dn);
  ((int4*)dst)[lane] = u.i4;  // 16 B/lane, coalesced

  if (lane == 0) {
    if (isW) {
      float n = fmaxf(sqrtf(ss), 1e-7f);
      float t = tanhf(n);           // c=1: tanh(sqrt_c * norm)
      float tc = fminf(t, 0.95f);   // radius clip folded into scale
      fscale[gw] = tc / n;          // proto = fscale * w
      float ys = tc * tc;           // ||proto||^2
      ysqA[gw] = ys;
      yrA[gw] = 1.f / (1.f - fminf(ys, 1.f - 1e-5f));
    } else {
      int r = gw - Cn;
      xsA[r] = ss;
      xrA[r] = 1.f / (1.f - fminf(ss, 1.f - 1e-5f));
    }
  }
}

// ------- bf16 MFMA GEMM: 128x256 block, 64x128 wave tiles, vmcnt pipeline -------
// DS-pipe was the R6 limiter (32KB read + 16KB write per 128x128-block-iter vs
// 155 MFMA cyc, plus a 4-way read conflict from the broken (r&3) swizzle).
// This round: (1) swizzle c^( (r>>1)&3 ): the 8 same-parity rows of a b128
// read now cycle all 4 columns -> every bank exactly 2-way = free (m136).
// (2) wave tile 64x128 (block 128x256, acc 4x8): 24KB write + 48KB read per
// block-iter for 2x the FLOPs = 25% less DS traffic per FLOP.
// Keeps R6's global_load_lds + s_waitcnt vmcnt(6) + raw-barrier pipeline
// (depth-2 flight; no vmcnt(0) drain in the loop).
__global__ __launch_bounds__(256, 2) void gemm_kernel(
    const __hip_bfloat16* __restrict__ xbf, const __hip_bfloat16* __restrict__ wbf,
    const float* __restrict__ fscale, const float* __restrict__ ysqA,
    const float* __restrict__ yrA, const float* __restrict__ xsA,
    const float* __restrict__ xrA, float* __restrict__ partials)
{
  __shared__ int4 ldsv[3072];  // 48 KB: buf{0,1} x [A 8K][W 16K]
  char* lds = (char*)ldsv;

  const int bid = blockIdx.x;           // 1024 blocks
  const int xcd = bid & 7;              // round-robin dispatch across XCDs
  const int loc = bid >> 3;             // 0..127
  const int mt  = loc & 15;             // 16 m-tiles of 128 (m fastest: share W band)
  const int nt  = (xcd << 3) | (loc >> 4);  // 64 n-tiles of 256, banded per XCD
  const int mBase = mt * 128;
  const int nBase = nt * 256;
  const int tid = threadIdx.x;
  const int lane = tid & 63;
  const int wave = tid >> 6;
  const int quad = lane >> 4;
  const int l16 = lane & 15;
  const int waveM = wave >> 1;          // 2 x 64 rows
  const int waveN = wave & 1;           // 2 x 128 cols

  v4f acc[4][8];
  #pragma unroll
  for (int i = 0; i < 4; ++i)
    #pragma unroll
    for (int j = 0; j < 8; ++j)
      acc[i][j] = (v4f){0.f, 0.f, 0.f, 0.f};

  // staging. A tile: 128 rows x 64 B = 512 chunks (2/thread); W: 256 rows = 1024
  // chunks (4/thread). slot s: r=s>>2, slot-col s&3, global col (s&3)^((r>>1)&3).
  const int sA0 = tid, sA1 = tid + 256;
  const int rA0 = sA0 >> 2, cA0 = (sA0 & 3) ^ ((rA0 >> 1) & 3);
  const int rA1 = sA1 >> 2, cA1 = (sA1 & 3) ^ ((rA1 >> 1) & 3);
  const char* gA0 = (const char*)xbf + (size_t)(mBase + rA0) * (Dn * 2) + cA0 * 16;
  const char* gA1 = (const char*)xbf + (size_t)(mBase + rA1) * (Dn * 2) + cA1 * 16;
  const int loA0 = sA0 * 16, loA1 = sA1 * 16;
  const char* gW[4]; int loW[4];
  #pragma unroll
  for (int p = 0; p < 4; ++p) {
    int s = tid + p * 256;
    int r = s >> 2, c = (s & 3) ^ ((r >> 1) & 3);
    gW[p] = (const char*)wbf + (size_t)(nBase + r) * (Dn * 2) + c * 16;
    loW[p] = s * 16;
  }

  // frag read offsets (swizzle-aware), relative to A / W region bases
  int aoffs[4], boffs[8];
  #pragma unroll
  for (int i = 0; i < 4; ++i) {
    int ra = waveM * 64 + i * 16 + l16;
    aoffs[i] = ra * 64 + ((quad ^ ((ra >> 1) & 3)) * 16);
  }
  #pragma unroll
  for (int j = 0; j < 8; ++j) {
    int rb = waveN * 128 + j * 16 + l16;
    boffs[j] = rb * 64 + ((quad ^ ((rb >> 1) & 3)) * 16);
  }

  // prologue: tiles 0,1 -> buffers 0,1 (12 loads in flight per thread-wave)
  #pragma unroll
  for (int t = 0; t < 2; ++t) {
    char* Ab = lds + t * 24576;
    char* Wb = Ab + 8192;
    async16(gA0 + t * 64, Ab + loA0);
    async16(gA1 + t * 64, Ab + loA1);
    #pragma unroll
    for (int p = 0; p < 4; ++p) async16(gW[p] + t * 64, Wb + loW[p]);
  }

  #pragma unroll
  for (int kt = 0; kt < 16; ++kt) {
    const int cur = kt & 1;
    if (kt < 15) { WAIT_VM6(); } else { WAIT_VM0(); }  // buf[cur]'s 6 loads landed
    RAW_BAR();                                          // ...for ALL waves
    char* Ab = lds + cur * 24576;
    char* Wb = Ab + 8192;
    v8bf af[4], bfv[8];
    #pragma unroll
    for (int i = 0; i < 4; ++i) af[i] = *(const v8bf*)(Ab + aoffs[i]);
    #pragma unroll
    for (int j = 0; j < 8; ++j) bfv[j] = *(const v8bf*)(Wb + boffs[j]);
    LGKM0_BAR();  // all waves' reads of buf[cur] done -> safe to rewrite it
    if (kt + 2 < 16) {  // tile kt+2 into buf[cur]: ~2 iters of flight
      async16(gA0 + (kt + 2) * 64, Ab + loA0);
      async16(gA1 + (kt + 2) * 64, Ab + loA1);
      #pragma unroll
      for (int p = 0; p < 4; ++p) async16(gW[p] + (kt + 2) * 64, Wb + loW[p]);
    }
    #pragma unroll
    for (int i = 0; i < 4; ++i)
      #pragma unroll
      for (int j = 0; j < 8; ++j)
        acc[i][j] = __builtin_amdgcn_mfma_f32_16x16x32_bf16(af[i], bfv[j], acc[i][j], 0, 0, 0);
  }

  // ---- epilogue: partial sums of e^{u}, u = 128*sims (e^{+64}-scaled) ----
  float ysqj[8], yrj[8], gj[8];
  #pragma unroll
  for (int j = 0; j < 8; ++j) {
    int col = nBase + waveN * 128 + j * 16 + l16;
    gj[j] = -2.f * fscale[col];
    ysqj[j] = ysqA[col];
    yrj[j] = yrA[col];
  }
  #pragma unroll
  for (int i = 0; i < 4; ++i) {
    #pragma unroll
    for (int r = 0; r < 4; ++r) {
      int row = mBase + waveM * 64 + i * 16 + quad * 4 + r;
      float xs = xsA[row];
      float xr2 = 2.f * xrA[row];
      float partial = 0.f;
      if (xs >= 0.99999f) {
        // clipped row: xr=1e5 -> z large -> u=64/z small.
        // sims~=1/(2z) (rel err 1/(4z^2)); e^u ~= 1+u+u^2/2 (err u^3/6).
        #pragma unroll
        for (int j = 0; j < 8; ++j) {
          float d = fmaxf(fmaf(gj[j], acc[i][j][r], xs + ysqj[j]), 0.f);
          float z = fmaf(d, xr2 * yrj[j], 1.f);
          float u = 64.f * __builtin_amdgcn_rcpf(z);
          partial += fmaf(u, fmaf(0.5f, u, 1.f), 1.f);
        }
      } else {
        // rare unclipped row: exact path
        #pragma unroll
        for (int j = 0; j < 8; ++j) {
          float d = fmaxf(fmaf(gj[j], acc[i][j][r], xs + ysqj[j]), 0.f);
          float z = fmaf(d, xr2 * yrj[j], 1.f);
          float sq = sqrtf(fmaf(z, z, -1.f));
          float u = 128.f * __builtin_amdgcn_rcpf(z + sq);
          partial += __expf(u);
        }
      }
      partial += __shfl_xor(partial, 1);
      partial += __shfl_xor(partial, 2);
      partial += __shfl_xor(partial, 4);
      partial += __shfl_xor(partial, 8);
      if (l16 == 0) partials[(size_t)row * 128 + nt * 2 + waveN] = partial;
    }
  }
}

// ---------------- final: label fix + row term + grid mean (atomic) ----------------
// partials are e^{+64}-scaled: S = sum_j e^{u_j}. term = -64 + log(S - e^{u_lab}
// + e^{64(phi+1)}) - 64*phi.
__global__ __launch_bounds__(256) void final_kernel(
    const float* __restrict__ x, const float* __restrict__ w,
    const int* __restrict__ labels, const float* __restrict__ fscale,
    const float* __restrict__ ysqA, const float* __restrict__ yrA,
    const float* __restrict__ xsA, const float* __restrict__ xrA,
    const float* __restrict__ partials, float* __restrict__ out)
{
  int row = blockIdx.x * 4 + (threadIdx.x >> 6);  // wave per row
  int lane = threadIdx.x & 63;
  const float* pr = partials + (size_t)row * 128;
  float sum = pr[lane] + pr[lane + 64];

  int lab = labels[row];
  const float4* xv = (const float4*)(x + (size_t)row * Dn);
  const float4* wv = (const float4*)(w + (size_t)lab * Dn);
  float4 a0 = xv[lane * 2], a1 = xv[lane * 2 + 1];
  float4 b0 = wv[lane * 2], b1 = wv[lane * 2 + 1];
  float dot = a0.x * b0.x + a0.y * b0.y + a0.z * b0.z + a0.w * b0.w
            + a1.x * b1.x + a1.y * b1.y + a1.z * b1.z + a1.w * b1.w;
  #pragma unroll
  for (int d = 1; d < 64; d <<= 1) {
    sum += __shfl_xor(sum, d);
    dot += __shfl_xor(dot, d);
  }

  __shared__ float red[4];
  if (lane == 0) {
    float xy = fscale[lab] * dot;  // fp32 exact label logit
    float diff = fmaxf(xsA[row] + ysqA[lab] - 2.f * xy, 0.f);
    float z = fmaf(2.f * diff, xrA[row] * yrA[lab], 1.f);
    float sq = sqrtf(fmaf(z, z, -1.f));
    float sims = 1.f / (z + sq);
    float u_lab = 128.f * sims;
    float cosv = fmaf(2.f, sims, -1.f);
    float sine = sqrtf(fmaxf(fmaf(-cosv, cosv, 1.f), 1e-7f));
    float phi = (cosv > -0.8775825619f)
                    ? (cosv * 0.8775825619f - sine * 0.4794255386f)
                    : (cosv - 0.2397127693f);
    float e_lab = __expf(u_lab);                          // e^{+64}-scaled cos term
    float e_phi = __expf(fminf(64.f * phi + 64.f, 80.f)); // scaled margin term
    red[threadIdx.x >> 6] = logf(sum - e_lab + e_phi) - 64.f * phi - 64.f;
  }
  __syncthreads();
  if (threadIdx.x == 0)
    atomicAdd(out, (red[0] + red[1] + red[2] + red[3]) * (1.f / (float)Bn));
}

extern "C" void kernel_launch(void* const* d_in, const int* in_sizes, int n_in,
                              void* d_out, int out_size, void* d_ws, size_t ws_size,
                              hipStream_t stream) {
  (void)in_sizes; (void)n_in; (void)out_size; (void)ws_size;
  const float* emb = (const float*)d_in[0];
  const int* labels = (const int*)d_in[1];
  const float* weight = (const float*)d_in[2];
  float* out = (float*)d_out;

  char* p = (char*)d_ws;
  __hip_bfloat16* wbf = (__hip_bfloat16*)p; p += (size_t)Cn * Dn * 2;  // 16 MB
  __hip_bfloat16* xbf = (__hip_bfloat16*)p; p += (size_t)Bn * Dn * 2;  // 2 MB
  float* fscale = (float*)p; p += (size_t)Cn * 4;
  float* ysqA  = (float*)p; p += (size_t)Cn * 4;
  float* yrA   = (float*)p; p += (size_t)Cn * 4;
  float* xsA   = (float*)p; p += (size_t)Bn * 4;
  float* xrA   = (float*)p; p += (size_t)Bn * 4;
  float* partials = (float*)p; p += (size_t)Bn * 128 * 4;  // 1 MB, written-once

  hipMemsetAsync(out, 0, sizeof(float), stream);  // atomicAdd target
  prep_kernel<<<(Cn + Bn) / 4, 256, 0, stream>>>(weight, emb, wbf, xbf, fscale, ysqA, yrA, xsA, xrA);
  gemm_kernel<<<(Bn / 128) * (Cn / 256), 256, 0, stream>>>(
      xbf, wbf, fscale, ysqA, yrA, xsA, xrA, partials);
  final_kernel<<<Bn / 4, 256, 0, stream>>>(emb, weight, labels, fscale, ysqA, yrA, xsA, xrA, partials, out);
}